// Round 1
// baseline (386.707 us; speedup 1.0000x reference)
//
#include <hip/hip_runtime.h>
#include <hip/hip_bf16.h>
#include <stdint.h>

// ResNetV1 sparse conv block, MI355X (gfx950).
// out = relu( conv(relu(conv(x,W0)), W1) + x ),  conv[n,d] = sum_k sum_c x[idx[n,k],c] * W[k,c,d]
// N=150000, K=27, C=64.
// Strategy: bf16 MFMA (16x16x32). Prep: x -> bf16; W -> bf16 packed in B-fragment order.
// Conv kernel: 128-row M-tile per block, 4 waves; per k: gather A-tile (XOR-swizzled LDS),
// stage packed W[k] tile, 16 MFMA per wave.

typedef __attribute__((ext_vector_type(8))) short short8;
typedef __attribute__((ext_vector_type(4))) float f32x4;

#define NV 150000
#define KOFF 27
// per-block rows
#define MT 128

static __device__ __forceinline__ ushort f2bf(float f) {
  union { float f; uint32_t u; } v; v.f = f;
  uint32_t u = v.u;
  return (ushort)((u + 0x7fffu + ((u >> 16) & 1u)) >> 16);
}

// Convert fp32 -> bf16 bits, 4 elements/thread.
__global__ void cvt_x_kernel(const float* __restrict__ x, ushort* __restrict__ xb, int n) {
  int i = blockIdx.x * 256 + threadIdx.x;
  if (i * 4 >= n) return;
  float4 v = ((const float4*)x)[i];
  ushort4 o;
  o.x = f2bf(v.x); o.y = f2bf(v.y); o.z = f2bf(v.z); o.w = f2bf(v.w);
  ((ushort4*)xb)[i] = o;
}

// Pack W [27][64][64] fp32 into bf16 B-fragment order:
// flat = (((k*2+s)*4+ct)*64 + lane)*8 + j  <-  W[k][c=s*32+(lane>>4)*8+j][d=ct*16+(lane&15)]
__global__ void pack_w_kernel(const float* __restrict__ W, ushort* __restrict__ wp, int total) {
  int o = blockIdx.x * 256 + threadIdx.x;
  if (o >= total) return;
  int j  = o & 7;
  int l  = (o >> 3) & 63;
  int ct = (o >> 9) & 3;
  int s  = (o >> 11) & 1;
  int k  = o >> 12;
  int c  = s * 32 + (l >> 4) * 8 + j;
  int d  = ct * 16 + (l & 15);
  wp[o] = f2bf(W[(k * 64 + c) * 64 + d]);
}

// MODE 0: y = relu(conv(feat,W)), store bf16 to out_bf
// MODE 1: y = relu(conv(feat,W) + resid), store fp32 to out_f
template <int MODE>
__global__ __launch_bounds__(256) void conv_kernel(
    const ushort* __restrict__ feat,   // [N,64] bf16 bits
    const int*    __restrict__ nbr,    // [N,27]
    const ushort* __restrict__ wp,     // packed W, 27*4096 bf16
    const float*  __restrict__ resid,  // [N,64] fp32 (MODE 1)
    ushort*       __restrict__ out_bf, // MODE 0
    float*        __restrict__ out_f,  // MODE 1
    int n) {
  __shared__ __align__(16) ushort sA[MT * 64];    // 16 KB, XOR-swizzled 16B chunks
  __shared__ __align__(16) ushort sB[4096];       // 8 KB, packed W tile for current k
  __shared__ int sIdx[MT * KOFF];                 // 13.5 KB

  const int tid  = threadIdx.x;
  const int m0   = blockIdx.x * MT;
  const int wave = tid >> 6;
  const int lane = tid & 63;
  const int quad = lane >> 4;
  const int lo   = lane & 15;

  // Stage neighbor indices for this block's rows (contiguous in memory).
  {
    const int cnt = (n - m0) >= MT ? MT * KOFF : (n - m0) * KOFF;
    const int base = m0 * KOFF;
    #pragma unroll
    for (int u = tid; u < MT * KOFF; u += 256)
      sIdx[u] = (u < cnt) ? nbr[base + u] : 0;
  }

  f32x4 acc[2][4];
  #pragma unroll
  for (int rt = 0; rt < 2; ++rt)
    #pragma unroll
    for (int ct = 0; ct < 4; ++ct)
      acc[rt][ct] = (f32x4)0.0f;

  __syncthreads();

  for (int k = 0; k < KOFF; ++k) {
    // Stage B tile: 8 KB contiguous copy of packed W[k].
    {
      const float4* wsrc = (const float4*)(wp + k * 4096);
      #pragma unroll
      for (int u = tid; u < 512; u += 256)
        ((float4*)sB)[u] = wsrc[u];
    }
    // Stage A tile: gather 128 rows x 128 B. unit u: row=u>>3, 16B seg=u&7.
    #pragma unroll
    for (int u = tid; u < MT * 8; u += 256) {
      int row = u >> 3, seg = u & 7;
      int g = sIdx[row * KOFF + k];
      float4 v = ((const float4*)(feat + g * 64))[seg];
      int chunk = seg ^ (row & 7);
      ((float4*)sA)[row * 8 + chunk] = v;
    }
    __syncthreads();

    const short8* sBv = (const short8*)sB;
    const short8* sAv = (const short8*)sA;
    #pragma unroll
    for (int s = 0; s < 2; ++s) {
      short8 b[4];
      #pragma unroll
      for (int ct = 0; ct < 4; ++ct)
        b[ct] = sBv[(s * 4 + ct) * 64 + lane];
      #pragma unroll
      for (int rt = 0; rt < 2; ++rt) {
        int row = wave * 32 + rt * 16 + lo;
        int chunk = (s * 4 + quad) ^ (row & 7);
        short8 a = sAv[row * 8 + chunk];
        #pragma unroll
        for (int ct = 0; ct < 4; ++ct)
          acc[rt][ct] = __builtin_amdgcn_mfma_f32_16x16x32_bf16(a, b[ct], acc[rt][ct], 0, 0, 0);
      }
    }
    __syncthreads();
  }

  // Epilogue. D layout: acc[rt][ct][j] = out[m0 + wave*32 + rt*16 + quad*4 + j][ct*16 + lo]
  #pragma unroll
  for (int rt = 0; rt < 2; ++rt) {
    int rbase = m0 + wave * 32 + rt * 16 + quad * 4;
    #pragma unroll
    for (int ct = 0; ct < 4; ++ct) {
      int col = ct * 16 + lo;
      #pragma unroll
      for (int j = 0; j < 4; ++j) {
        int r = rbase + j;
        if (r < n) {
          float v = acc[rt][ct][j];
          if (MODE == 0) {
            v = v > 0.0f ? v : 0.0f;
            out_bf[r * 64 + col] = f2bf(v);
          } else {
            v += resid[r * 64 + col];
            v = v > 0.0f ? v : 0.0f;
            out_f[r * 64 + col] = v;
          }
        }
      }
    }
  }
}

extern "C" void kernel_launch(void* const* d_in, const int* in_sizes, int n_in,
                              void* d_out, int out_size, void* d_ws, size_t ws_size,
                              hipStream_t stream) {
  const float* x   = (const float*)d_in[0];  // [150000,64] fp32
  const int*   nbr = (const int*)d_in[1];    // [150000,27] int32
  const float* W0  = (const float*)d_in[2];  // [27,64,64] fp32
  const float* W1  = (const float*)d_in[3];
  float* out = (float*)d_out;

  const int n = NV;
  const int nc = NV * 64;          // 9,600,000
  const int wtot = KOFF * 4096;    // 110,592

  // Workspace layout (all 16B-aligned): xb[9.6M] yb[9.6M] wp0[110592] wp1[110592] bf16
  ushort* xb  = (ushort*)d_ws;
  ushort* yb  = xb + nc;
  ushort* wp0 = yb + nc;
  ushort* wp1 = wp0 + wtot;

  cvt_x_kernel<<<(nc / 4 + 255) / 256, 256, 0, stream>>>(x, xb, nc);
  pack_w_kernel<<<(wtot + 255) / 256, 256, 0, stream>>>(W0, wp0, wtot);
  pack_w_kernel<<<(wtot + 255) / 256, 256, 0, stream>>>(W1, wp1, wtot);

  const int grid = (n + MT - 1) / MT;  // 1172
  conv_kernel<0><<<grid, 256, 0, stream>>>(xb, nbr, wp0, nullptr, yb, nullptr, n);
  conv_kernel<1><<<grid, 256, 0, stream>>>(yb, nbr, wp1, x, nullptr, out, n);
}